// Round 3
// baseline (1456.461 us; speedup 1.0000x reference)
//
#include <hip/hip_runtime.h>
#include <math.h>

#define BATCH 64
#define SLEN  480050          // 200 + 150*3199
#define TFR   3200            // frames
#define FLEN  200             // frame length
#define FSH   150             // shift
#define NBINS 128             // kept DFT bins
#define EPSF  1e-7f

// ws layout in floats
#define WS_SUM 0              // 64*32 partial sums
#define WS_MU  2048           // 64
#define WS_OR  2112           // 128  sum_l cos
#define WS_OI  2240           // 128  sum_l sin
#define WS_TAB 2368           // 200*256: [l][cos 0..127 | sin 0..127]

__global__ __launch_bounds__(256) void k_sum_partial(const float* __restrict__ x,
                                                     float* __restrict__ ws) {
    int blk = blockIdx.x;          // 64*32
    int b = blk >> 5, c = blk & 31;
    const float2* row = (const float2*)(x + (size_t)b * SLEN);
    const int n2 = SLEN / 2;       // 240025
    const int per = (n2 + 31) / 32;
    int start = c * per;
    int end = start + per; if (end > n2) end = n2;
    float s = 0.f;
    for (int i = start + threadIdx.x; i < end; i += 256) {
        float2 v = row[i];
        s += v.x + v.y;
    }
    #pragma unroll
    for (int off = 1; off < 64; off <<= 1) s += __shfl_xor(s, off);
    __shared__ float ls[4];
    int wave = threadIdx.x >> 6, lane = threadIdx.x & 63;
    if (lane == 0) ls[wave] = s;
    __syncthreads();
    if (threadIdx.x == 0)
        ws[WS_SUM + b * 32 + c] = ls[0] + ls[1] + ls[2] + ls[3];
}

__global__ __launch_bounds__(64) void k_final(float* __restrict__ ws) {
    int b = threadIdx.x;
    if (b < BATCH) {
        float s = 0.f;
        #pragma unroll
        for (int c = 0; c < 32; ++c) s += ws[WS_SUM + b * 32 + c];
        ws[WS_MU + b] = s / (float)SLEN;
    }
}

// build fused table [l][256] = [cos(n) | sin(n)] and the per-bin window sums
__global__ __launch_bounds__(256) void k_tab(const float* __restrict__ rk,
                                             const float* __restrict__ ik,
                                             float* __restrict__ ws) {
    int n = blockIdx.x;            // 0..127
    int l = threadIdx.x;           // 0..255
    float cr = 0.f, ci = 0.f;
    if (l < FLEN) {
        cr = rk[n * FLEN + l];
        ci = ik[n * FLEN + l];
        ws[WS_TAB + l * 256 + n]       = cr;
        ws[WS_TAB + l * 256 + 128 + n] = ci;
    }
    #pragma unroll
    for (int off = 1; off < 64; off <<= 1) {
        cr += __shfl_xor(cr, off);
        ci += __shfl_xor(ci, off);
    }
    __shared__ float lr[4], li[4];
    int wave = threadIdx.x >> 6, lane = threadIdx.x & 63;
    if (lane == 0) { lr[wave] = cr; li[wave] = ci; }
    __syncthreads();
    if (threadIdx.x == 0) {
        ws[WS_OR + n] = lr[0] + lr[1] + lr[2] + lr[3];
        ws[WS_OI + n] = li[0] + li[1] + li[2] + li[3];
    }
}

// load 4 l-rows of the table (cos+sin, 4 bins each) into registers
#define LOADT(C, S, L) {                                    \
    C[0] = tab[(size_t)((L) + 0) * 64 + nq];                \
    S[0] = tab[(size_t)((L) + 0) * 64 + 32 + nq];           \
    C[1] = tab[(size_t)((L) + 1) * 64 + nq];                \
    S[1] = tab[(size_t)((L) + 1) * 64 + 32 + nq];           \
    C[2] = tab[(size_t)((L) + 2) * 64 + nq];                \
    S[2] = tab[(size_t)((L) + 2) * 64 + 32 + nq];           \
    C[3] = tab[(size_t)((L) + 3) * 64 + nq];                \
    S[3] = tab[(size_t)((L) + 3) * 64 + 32 + nq];           }

#define FMABLK(C, S, L) {                                   \
    _Pragma("unroll")                                       \
    for (int tt = 0; tt < 4; ++tt) {                        \
        float4 f = *(const float4*)&frame[tl0 + tt][(L)];   \
        float fv[4] = { f.x, f.y, f.z, f.w };               \
        _Pragma("unroll")                                   \
        for (int k = 0; k < 4; ++k) {                       \
            ar[tt][0] = fmaf(fv[k], C[k].x, ar[tt][0]);     \
            ar[tt][1] = fmaf(fv[k], C[k].y, ar[tt][1]);     \
            ar[tt][2] = fmaf(fv[k], C[k].z, ar[tt][2]);     \
            ar[tt][3] = fmaf(fv[k], C[k].w, ar[tt][3]);     \
            ai[tt][0] = fmaf(fv[k], S[k].x, ai[tt][0]);     \
            ai[tt][1] = fmaf(fv[k], S[k].y, ai[tt][1]);     \
            ai[tt][2] = fmaf(fv[k], S[k].z, ai[tt][2]);     \
            ai[tt][3] = fmaf(fv[k], S[k].w, ai[tt][3]);     \
        }                                                   \
    }                                                       }

// main fused kernel: block = 32 frames x 128 bins, thread tile = 4 frames x 4 bins
__global__ __launch_bounds__(256) void k_main(const float* __restrict__ x,
                                              const float* __restrict__ ws,
                                              float* __restrict__ out) {
    __shared__ float frame[32][204];   // pitch 204 floats (16B-aligned rows), 26.1 KB

    int b  = blockIdx.y;
    int t0 = blockIdx.x * 32;
    int tid = threadIdx.x;
    const float* xb = x + (size_t)b * SLEN;

    // stage 32 raw frames: 8 threads per row, float2 copies (row base 600B -> 8B aligned)
    {
        int rt = tid >> 3, rq = tid & 7;
        const float2* src = (const float2*)(xb + (size_t)(t0 + rt) * FSH);
        float2* dst = (float2*)frame[rt];
        #pragma unroll
        for (int i = rq; i < 100; i += 8) dst[i] = src[i];
    }
    __syncthreads();

    int nq  = tid & 31;        // bin group of 4
    int tq  = tid >> 5;        // frame group of 4
    int n0  = nq * 4;
    int tl0 = tq * 4;

    const float4* tab = (const float4*)(ws + WS_TAB);

    float ar[4][4], ai[4][4];
    #pragma unroll
    for (int tt = 0; tt < 4; ++tt)
        #pragma unroll
        for (int nn = 0; nn < 4; ++nn) { ar[tt][nn] = 0.f; ai[tt][nn] = 0.f; }

    // double-buffered register prefetch of the table: while FMA-ing chunk A(l),
    // chunk B(l+4) is already resident; A's reload (l+8) is issued before B's
    // FMAs, so ~128 FMAs (~256+ cy of issue) cover the L2 load latency.
    float4 ca[4], sa[4], cb[4], sb[4];
    LOADT(ca, sa, 0);
    LOADT(cb, sb, 4);

    for (int l = 0; l < FLEN; l += 8) {
        FMABLK(ca, sa, l);
        int lnA = (l + 8 < FLEN) ? l + 8 : 0;    // harmless wrap reload on last iter
        LOADT(ca, sa, lnA);
        FMABLK(cb, sb, l + 4);
        int lnB = (l + 8 < FLEN) ? l + 12 : 4;
        LOADT(cb, sb, lnB);
    }

    // epilogue: mean-correction (DFT linearity), magnitude, log10.
    // The 1/(sd+eps) batch factor is a constant log-shift and cancels exactly
    // in the per-(b,t) bin normalization below, so it is never computed.
    float mu = ws[WS_MU + b];
    float4 orv = *(const float4*)(ws + WS_OR + n0);
    float4 oiv = *(const float4*)(ws + WS_OI + n0);
    float orr[4] = { orv.x, orv.y, orv.z, orv.w };
    float oii[4] = { oiv.x, oiv.y, oiv.z, oiv.w };

    float v[4][4];
    #pragma unroll
    for (int tt = 0; tt < 4; ++tt) {
        #pragma unroll
        for (int nn = 0; nn < 4; ++nn) {
            float re = ar[tt][nn] - mu * orr[nn];
            float im = ai[tt][nn] - mu * oii[nn];
            float m = sqrtf(fmaf(re, re, im * im));
            m = fmaxf(m, EPSF);
            v[tt][nn] = __log2f(m) * 0.3010299956639812f;   // log10
        }
    }

    // per-(b,t) normalization over the 128 bins (32 lanes x 4 regs)
    #pragma unroll
    for (int tt = 0; tt < 4; ++tt) {
        float s = (v[tt][0] + v[tt][1]) + (v[tt][2] + v[tt][3]);
        float q = fmaf(v[tt][0], v[tt][0], v[tt][1] * v[tt][1])
                + fmaf(v[tt][2], v[tt][2], v[tt][3] * v[tt][3]);
        #pragma unroll
        for (int off = 1; off < 32; off <<= 1) {
            s += __shfl_xor(s, off);
            q += __shfl_xor(q, off);
        }
        float mean = s * (1.0f / 128.0f);
        float var  = q * (1.0f / 128.0f) - mean * mean;
        float sd   = sqrtf(fmaxf(var, 0.f));
        float sc   = 1.0f / (sd + EPSF);
        #pragma unroll
        for (int nn = 0; nn < 4; ++nn)
            v[tt][nn] = (v[tt][nn] - mean) * sc;
    }

    // write out[b][n][t]: one float4 per bin over 4 consecutive t (exact, no RMW)
    float* ob = out + (size_t)b * NBINS * TFR + t0 + tl0;
    #pragma unroll
    for (int nn = 0; nn < 4; ++nn) {
        float4 w = make_float4(v[0][nn], v[1][nn], v[2][nn], v[3][nn]);
        *(float4*)(ob + (size_t)(n0 + nn) * TFR) = w;
    }
}

extern "C" void kernel_launch(void* const* d_in, const int* in_sizes, int n_in,
                              void* d_out, int out_size, void* d_ws, size_t ws_size,
                              hipStream_t stream) {
    const float* x  = (const float*)d_in[0];
    const float* rk = (const float*)d_in[1];
    const float* ik = (const float*)d_in[2];
    float* out = (float*)d_out;
    float* ws  = (float*)d_ws;

    k_sum_partial<<<BATCH * 32, 256, 0, stream>>>(x, ws);
    k_final<<<1, 64, 0, stream>>>(ws);
    k_tab<<<NBINS, 256, 0, stream>>>(rk, ik, ws);
    k_main<<<dim3(TFR / 32, BATCH), 256, 0, stream>>>(x, ws, out);
}

// Round 5
// 316.357 us; speedup vs baseline: 4.6039x; 4.6039x over previous
//
#include <hip/hip_runtime.h>
#include <math.h>
#include <stdint.h>

#define BATCH 64
#define SLEN  480050          // 200 + 150*3199
#define TFR   3200            // frames
#define FLEN  200             // frame length
#define FSH   150             // shift
#define NBINS 128             // kept DFT bins
#define NCOL  256             // 128 cos | 128 sin
#define NKC   7               // K chunks of 32 (K padded to 224)

// ws layout (float indices unless noted)
#define WS_SUM 0              // 64*32 partial sums
#define WS_MU  2048           // 64
#define WS_OR  2112           // 128  sum_l cos(n,l)  (fp32 exact)
#define WS_OI  2240           // 128  sum_l sin(n,l)
#define WS_TABI_BYTES 16384   // table image: NKC chunks * 32768 B ([hi 16K][lo 16K])

typedef __attribute__((ext_vector_type(8))) short bf16x8;
typedef __attribute__((ext_vector_type(4))) float f32x4;

__device__ inline unsigned pack2bf(float a, float b) {
    unsigned ua = __builtin_bit_cast(unsigned, a);
    unsigned ub = __builtin_bit_cast(unsigned, b);
    ua = (ua + 0x7FFFu + ((ua >> 16) & 1u)) >> 16;   // RNE to bf16
    ub = (ub + 0x7FFFu + ((ub >> 16) & 1u)) >> 16;
    return ua | (ub << 16);
}

__device__ inline void gll16(const void* g, void* l) {
    __builtin_amdgcn_global_load_lds(
        (const __attribute__((address_space(1))) void*)g,
        (__attribute__((address_space(3))) void*)l, 16, 0, 0);
}

__global__ __launch_bounds__(256) void k_sum_partial(const float* __restrict__ x,
                                                     float* __restrict__ ws) {
    int blk = blockIdx.x;          // 64*32
    int b = blk >> 5, c = blk & 31;
    const float2* row = (const float2*)(x + (size_t)b * SLEN);
    const int n2 = SLEN / 2;       // 240025
    const int per = (n2 + 31) / 32;
    int start = c * per;
    int end = start + per; if (end > n2) end = n2;
    float s = 0.f;
    for (int i = start + threadIdx.x; i < end; i += 256) {
        float2 v = row[i];
        s += v.x + v.y;
    }
    #pragma unroll
    for (int off = 1; off < 64; off <<= 1) s += __shfl_xor(s, off);
    __shared__ float ls[4];
    int wave = threadIdx.x >> 6, lane = threadIdx.x & 63;
    if (lane == 0) ls[wave] = s;
    __syncthreads();
    if (threadIdx.x == 0)
        ws[WS_SUM + b * 32 + c] = ls[0] + ls[1] + ls[2] + ls[3];
}

__global__ __launch_bounds__(64) void k_final(float* __restrict__ ws) {
    int b = threadIdx.x;
    if (b < BATCH) {
        float s = 0.f;
        #pragma unroll
        for (int c = 0; c < 32; ++c) s += ws[WS_SUM + b * 32 + c];
        ws[WS_MU + b] = s / (float)SLEN;
    }
}

// per-bin window sums (fp32 exact) for the epilogue mean-correction
__global__ __launch_bounds__(256) void k_colsum(const float* __restrict__ rk,
                                                const float* __restrict__ ik,
                                                float* __restrict__ ws) {
    int n = blockIdx.x;            // 0..127
    int l = threadIdx.x;           // 0..255
    float cr = 0.f, ci = 0.f;
    if (l < FLEN) {
        cr = rk[n * FLEN + l];
        ci = ik[n * FLEN + l];
    }
    #pragma unroll
    for (int off = 1; off < 64; off <<= 1) {
        cr += __shfl_xor(cr, off);
        ci += __shfl_xor(ci, off);
    }
    __shared__ float lr[4], li[4];
    int wave = threadIdx.x >> 6, lane = threadIdx.x & 63;
    if (lane == 0) { lr[wave] = cr; li[wave] = ci; }
    __syncthreads();
    if (threadIdx.x == 0) {
        ws[WS_OR + n] = lr[0] + lr[1] + lr[2] + lr[3];
        ws[WS_OI + n] = li[0] + li[1] + li[2] + li[3];
    }
}

// Build the split-bf16 table image (hi and lo planes), pre-swizzled per chunk:
// col c (0..255 = cos n | sin n), 64 B of k-pairs per chunk; 16B sub-block
// index XORed with ((c>>1)&3) so LDS b128 reads are conflict-free.
__global__ __launch_bounds__(256) void k_tabsplit(const float* __restrict__ rk,
                                                  const float* __restrict__ ik,
                                                  float* __restrict__ ws) {
    int e = blockIdx.x * 256 + threadIdx.x;      // 0..28671
    if (e >= NCOL * 112) return;
    int c = e / 112;
    int p = e - c * 112;                         // k-pair index, k = 2p
    int k = p * 2;
    int n = c & 127;
    const float* src = (c & 128) ? ik : rk;
    float v0 = (k     < FLEN) ? src[n * FLEN + k]     : 0.f;
    float v1 = (k + 1 < FLEN) ? src[n * FLEN + k + 1] : 0.f;
    unsigned hi = pack2bf(v0, v1);
    float h0 = __builtin_bit_cast(float, hi << 16);
    float h1 = __builtin_bit_cast(float, hi & 0xFFFF0000u);
    unsigned lo = pack2bf(v0 - h0, v1 - h1);
    int kc = k >> 5;
    int kb = (k & 31) * 2;                       // byte within 64B row
    int sb = (kb >> 4) ^ ((c >> 1) & 3);         // swizzled 16B sub-block
    char* base = (char*)ws + WS_TABI_BYTES + kc * 32768 + c * 64 + (sb << 4) + (kb & 15);
    *(unsigned*)base = hi;
    *(unsigned*)(base + 16384) = lo;
}

// Main: block = 64 frames x 256 cols, 4 waves; wave = 16 frames x all 16 N-tiles.
// Split-bf16 MFMA (AhBh + AlBh + AhBl), fp32 accum. A straight from global.
__global__ __launch_bounds__(256, 2) void k_main(const float* __restrict__ x,
                                                 const float* __restrict__ ws,
                                                 float* __restrict__ out) {
    __shared__ __align__(16) unsigned char smem[65536];  // 2 x [hi 16K | lo 16K]

    const int tid    = threadIdx.x;
    const int b      = blockIdx.y;
    const int t0     = blockIdx.x * 64;
    const int lane   = tid & 63;
    const int w      = tid >> 6;
    const int lanelo = lane & 15;
    const int lq     = lane >> 4;
    const int sbswz  = (lanelo >> 1) & 3;

    const float* xb  = x + (size_t)b * SLEN;
    const char* tabI = (const char*)ws + WS_TABI_BYTES;

    // prologue: stage chunk 0 -> buf0 (32 KB, 8 x 1KB segments per wave)
    #pragma unroll
    for (int i = 0; i < 8; ++i)
        gll16(tabI + (w * 8 + i) * 1024 + lane * 16, smem + (w * 8 + i) * 1024);
    __syncthreads();   // drains vmcnt -> buf0 ready

    f32x4 acc[16];
    #pragma unroll
    for (int nt = 0; nt < 16; ++nt) acc[nt] = (f32x4){0.f, 0.f, 0.f, 0.f};

    const float* arow = xb + (size_t)(t0 + w * 16 + lanelo) * FSH;

    for (int kc = 0; kc < NKC; ++kc) {
        // issue next chunk into the other buffer (hidden under this iter's work)
        if (kc < NKC - 1) {
            const char* src = tabI + (size_t)(kc + 1) * 32768;
            unsigned char* db = smem + ((kc + 1) & 1) * 32768;
            #pragma unroll
            for (int i = 0; i < 8; ++i)
                gll16(src + (w * 8 + i) * 1024 + lane * 16, db + (w * 8 + i) * 1024);
        }

        // A slice: 8 floats of this lane's frame row, split to bf16 hi/lo
        float a[8];
        if (kc < NKC - 1 || lq == 0) {
            const float2* s2 = (const float2*)(arow + kc * 32 + lq * 8);
            float2 p0 = s2[0], p1 = s2[1], p2 = s2[2], p3 = s2[3];
            a[0] = p0.x; a[1] = p0.y; a[2] = p1.x; a[3] = p1.y;
            a[4] = p2.x; a[5] = p2.y; a[6] = p3.x; a[7] = p3.y;
        } else {
            #pragma unroll
            for (int i = 0; i < 8; ++i) a[i] = 0.f;
        }
        unsigned hw[4], lw[4];
        #pragma unroll
        for (int q = 0; q < 4; ++q) {
            hw[q] = pack2bf(a[2 * q], a[2 * q + 1]);
            float h0 = __builtin_bit_cast(float, hw[q] << 16);
            float h1 = __builtin_bit_cast(float, hw[q] & 0xFFFF0000u);
            lw[q] = pack2bf(a[2 * q] - h0, a[2 * q + 1] - h1);
        }
        bf16x8 ah = __builtin_bit_cast(bf16x8, *(uint4*)hw);
        bf16x8 al = __builtin_bit_cast(bf16x8, *(uint4*)lw);

        const unsigned char* Bb = smem + (kc & 1) * 32768;
        #pragma unroll
        for (int nt = 0; nt < 16; ++nt) {
            int off = (nt * 16 + lanelo) * 64 + ((lq ^ sbswz) << 4);
            bf16x8 bh = *(const bf16x8*)(Bb + off);
            bf16x8 bl = *(const bf16x8*)(Bb + 16384 + off);
            acc[nt] = __builtin_amdgcn_mfma_f32_16x16x32_bf16(al, bh, acc[nt], 0, 0, 0);
            acc[nt] = __builtin_amdgcn_mfma_f32_16x16x32_bf16(ah, bl, acc[nt], 0, 0, 0);
            acc[nt] = __builtin_amdgcn_mfma_f32_16x16x32_bf16(ah, bh, acc[nt], 0, 0, 0);
        }
        __syncthreads();   // B reads done; next buffer committed
    }

    // ---- epilogue: mean-correction, log2 magnitude (log10 scale cancels) ----
    // acc[nt][j]: frame = t0 + w*16 + lq*4 + j, col = nt*16 + lanelo.
    // nt 0..7 = re of bin, nt+8 = im of the SAME bin, same lane.
    float mu = ws[WS_MU + b];
    float v[8][4];
    #pragma unroll
    for (int nt = 0; nt < 8; ++nt) {
        float orr = ws[WS_OR + nt * 16 + lanelo];
        float oii = ws[WS_OI + nt * 16 + lanelo];
        #pragma unroll
        for (int j = 0; j < 4; ++j) {
            float re = acc[nt][j]     - mu * orr;
            float im = acc[nt + 8][j] - mu * oii;
            float s = fmaf(re, re, im * im);
            float lg = 0.5f * __log2f(s);                 // log2(mag)
            v[nt][j] = fmaxf(lg, -23.2534966f);           // log2(1e-7) clamp
        }
    }
    // per-frame normalization over 128 bins: 8 in-lane x 16 lanes (same lq)
    #pragma unroll
    for (int j = 0; j < 4; ++j) {
        float s = 0.f, q = 0.f;
        #pragma unroll
        for (int nt = 0; nt < 8; ++nt) {
            s += v[nt][j];
            q = fmaf(v[nt][j], v[nt][j], q);
        }
        #pragma unroll
        for (int off = 1; off < 16; off <<= 1) {
            s += __shfl_xor(s, off);
            q += __shfl_xor(q, off);
        }
        float mean = s * (1.f / 128.f);
        float var  = fmaxf(q * (1.f / 128.f) - mean * mean, 0.f);
        float sc   = 1.f / (sqrtf(var) + 3.3219281e-7f);  // eps / log10(2)
        #pragma unroll
        for (int nt = 0; nt < 8; ++nt) v[nt][j] = (v[nt][j] - mean) * sc;
    }

    // ---- transpose via per-wave swizzled LDS region (after final barrier) ----
    float* Tw = (float*)(smem + w * 8192);
    #pragma unroll
    for (int nt = 0; nt < 8; ++nt) {
        int n = nt * 16 + lanelo;
        int swzl = (lq ^ (n & 3) ^ ((n >> 2) & 1)) << 2;
        *(float4*)(Tw + n * 16 + swzl) =
            make_float4(v[nt][0], v[nt][1], v[nt][2], v[nt][3]);
    }
    // same-wave LDS ordering: compiler inserts lgkmcnt before dependent reads
    float* ob = out + (size_t)b * NBINS * TFR + t0 + w * 16;
    #pragma unroll
    for (int p = 0; p < 2; ++p) {
        int n = p * 64 + lane;
        int sw = (n & 3) ^ ((n >> 2) & 1);
        float4 r0 = *(float4*)(Tw + n * 16 + ((0 ^ sw) << 2));
        float4 r1 = *(float4*)(Tw + n * 16 + ((1 ^ sw) << 2));
        float4 r2 = *(float4*)(Tw + n * 16 + ((2 ^ sw) << 2));
        float4 r3 = *(float4*)(Tw + n * 16 + ((3 ^ sw) << 2));
        float4* dst = (float4*)(ob + (size_t)n * TFR);
        dst[0] = r0; dst[1] = r1; dst[2] = r2; dst[3] = r3;
    }
}

extern "C" void kernel_launch(void* const* d_in, const int* in_sizes, int n_in,
                              void* d_out, int out_size, void* d_ws, size_t ws_size,
                              hipStream_t stream) {
    const float* x  = (const float*)d_in[0];
    const float* rk = (const float*)d_in[1];
    const float* ik = (const float*)d_in[2];
    float* out = (float*)d_out;
    float* ws  = (float*)d_ws;

    k_sum_partial<<<BATCH * 32, 256, 0, stream>>>(x, ws);
    k_final<<<1, 64, 0, stream>>>(ws);
    k_colsum<<<NBINS, 256, 0, stream>>>(rk, ik, ws);
    k_tabsplit<<<112, 256, 0, stream>>>(rk, ik, ws);
    k_main<<<dim3(TFR / 64, BATCH), 256, 0, stream>>>(x, ws, out);
}

// Round 6
// 314.196 us; speedup vs baseline: 4.6355x; 1.0069x over previous
//
#include <hip/hip_runtime.h>
#include <hip/hip_bf16.h>
#include <math.h>
#include <stdint.h>

#define BATCH 64
#define SLEN  480050          // 200 + 150*3199
#define TFR   3200            // frames
#define FLEN  200             // frame length
#define FSH   150             // shift
#define NBINS 128             // kept DFT bins
#define NCOL  256             // 128 cos | 128 sin
#define NKC   7               // K chunks of 32 (K padded to 224)

// ws layout (float indices unless noted)
#define WS_SUM 0              // 64*32 partial sums
#define WS_OR  2112           // 128  sum_l cos(n,l)  (fp32 exact)
#define WS_OI  2240           // 128  sum_l sin(n,l)
#define WS_TABI_BYTES 16384   // table image: NKC chunks * 32768 B ([hi 16K][lo 16K])

typedef __attribute__((ext_vector_type(8))) short bf16x8;
typedef __attribute__((ext_vector_type(4))) float f32x4;

__device__ inline unsigned pack2bf(float a, float b) {
    unsigned ua = __builtin_bit_cast(unsigned, a);
    unsigned ub = __builtin_bit_cast(unsigned, b);
    ua = (ua + 0x7FFFu + ((ua >> 16) & 1u)) >> 16;   // RNE to bf16
    ub = (ub + 0x7FFFu + ((ub >> 16) & 1u)) >> 16;
    return ua | (ub << 16);
}

__device__ inline void gll16(const void* g, void* l) {
    __builtin_amdgcn_global_load_lds(
        (const __attribute__((address_space(1))) void*)g,
        (__attribute__((address_space(3))) void*)l, 16, 0, 0);
}

// ---- one aux kernel, role by blockIdx ----
// blocks [0,2048): per-batch partial sums of x
// blocks [2048,2160): split-bf16 swizzled table image build
// blocks [2160,2288): per-bin window sums (fp32 exact)
__global__ __launch_bounds__(256) void k_aux(const float* __restrict__ x,
                                             const float* __restrict__ rk,
                                             const float* __restrict__ ik,
                                             float* __restrict__ ws) {
    int blk = blockIdx.x;
    if (blk < 2048) {
        int b = blk >> 5, c = blk & 31;
        const float2* row = (const float2*)(x + (size_t)b * SLEN);
        const int n2 = SLEN / 2;       // 240025
        const int per = (n2 + 31) / 32;
        int start = c * per;
        int end = start + per; if (end > n2) end = n2;
        float s = 0.f;
        for (int i = start + threadIdx.x; i < end; i += 256) {
            float2 v = row[i];
            s += v.x + v.y;
        }
        #pragma unroll
        for (int off = 1; off < 64; off <<= 1) s += __shfl_xor(s, off);
        __shared__ float ls[4];
        int wave = threadIdx.x >> 6, lane = threadIdx.x & 63;
        if (lane == 0) ls[wave] = s;
        __syncthreads();
        if (threadIdx.x == 0)
            ws[WS_SUM + b * 32 + c] = ls[0] + ls[1] + ls[2] + ls[3];
    } else if (blk < 2160) {
        // table image: col c (0..255 = cos n | sin n), 64 B of k-pairs per chunk;
        // 16B sub-block XORed with ((c>>1)&3) -> conflict-free LDS b128 reads.
        int e = (blk - 2048) * 256 + threadIdx.x;    // 0..28671
        int c = e / 112;
        int p = e - c * 112;                         // k-pair index, k = 2p
        int k = p * 2;
        int n = c & 127;
        const float* src = (c & 128) ? ik : rk;
        float v0 = (k     < FLEN) ? src[n * FLEN + k]     : 0.f;
        float v1 = (k + 1 < FLEN) ? src[n * FLEN + k + 1] : 0.f;
        unsigned hi = pack2bf(v0, v1);
        float h0 = __builtin_bit_cast(float, hi << 16);
        float h1 = __builtin_bit_cast(float, hi & 0xFFFF0000u);
        unsigned lo = pack2bf(v0 - h0, v1 - h1);
        int kc = k >> 5;
        int kb = (k & 31) * 2;                       // byte within 64B row
        int sb = (kb >> 4) ^ ((c >> 1) & 3);         // swizzled 16B sub-block
        char* base = (char*)ws + WS_TABI_BYTES + kc * 32768 + c * 64 + (sb << 4) + (kb & 15);
        *(unsigned*)base = hi;
        *(unsigned*)(base + 16384) = lo;
    } else {
        int n = blk - 2160;            // 0..127
        int l = threadIdx.x;
        float cr = 0.f, ci = 0.f;
        if (l < FLEN) {
            cr = rk[n * FLEN + l];
            ci = ik[n * FLEN + l];
        }
        #pragma unroll
        for (int off = 1; off < 64; off <<= 1) {
            cr += __shfl_xor(cr, off);
            ci += __shfl_xor(ci, off);
        }
        __shared__ float lr[4], li[4];
        int wave = threadIdx.x >> 6, lane = threadIdx.x & 63;
        if (lane == 0) { lr[wave] = cr; li[wave] = ci; }
        __syncthreads();
        if (threadIdx.x == 0) {
            ws[WS_OR + n] = lr[0] + lr[1] + lr[2] + lr[3];
            ws[WS_OI + n] = li[0] + li[1] + li[2] + li[3];
        }
    }
}

// split a lane's 8-float A slice into bf16 hi/lo fragments (HW cvt path)
__device__ inline void split8(const float* __restrict__ a, bf16x8& hv, bf16x8& lv) {
    #pragma unroll
    for (int i = 0; i < 8; ++i) {
        __hip_bfloat16 hb = __float2bfloat16(a[i]);
        float hf = __bfloat162float(hb);
        __hip_bfloat16 lb = __float2bfloat16(a[i] - hf);
        hv[i] = __builtin_bit_cast(short, hb);
        lv[i] = __builtin_bit_cast(short, lb);
    }
}

// Main: block = 128 frames x 256 cols, 4 waves; wave = 2 M-tiles (32 frames) x 16 N-tiles.
// Split-bf16 MFMA (AlBh + AhBl + AhBh), fp32 accum; each B-fragment feeds 6 MFMAs.
__global__ __launch_bounds__(256, 2) void k_main(const float* __restrict__ x,
                                                 const float* __restrict__ ws,
                                                 float* __restrict__ out) {
    __shared__ __align__(16) unsigned char smem[65536];  // 2 x [hi 16K | lo 16K]

    const int tid    = threadIdx.x;
    const int b      = blockIdx.y;
    const int t0     = blockIdx.x * 128;
    const int lane   = tid & 63;
    const int w      = tid >> 6;
    const int lanelo = lane & 15;
    const int lq     = lane >> 4;
    const int sbswz  = (lanelo >> 1) & 3;

    const float* xb  = x + (size_t)b * SLEN;
    const char* tabI = (const char*)ws + WS_TABI_BYTES;

    // batch mean from partials (uniform -> scalar path)
    float msum = 0.f;
    #pragma unroll
    for (int c = 0; c < 32; ++c) msum += ws[WS_SUM + b * 32 + c];
    const float mu = msum * (1.0f / (float)SLEN);

    // prologue: stage chunk 0 -> buf0 (32 KB, 8 x 1KB segments per wave)
    #pragma unroll
    for (int i = 0; i < 8; ++i)
        gll16(tabI + (w * 8 + i) * 1024 + lane * 16, smem + (w * 8 + i) * 1024);
    __syncthreads();   // drains vmcnt -> buf0 ready

    f32x4 acc[32];
    #pragma unroll
    for (int q = 0; q < 32; ++q) acc[q] = (f32x4){0.f, 0.f, 0.f, 0.f};

    const float* arow0 = xb + (size_t)(t0 + w * 32 + lanelo) * FSH;
    const float* arow1 = arow0 + (size_t)16 * FSH;

    for (int kc = 0; kc < NKC; ++kc) {
        // issue next chunk into the other buffer (hidden under this iter's work)
        if (kc < NKC - 1) {
            const char* src = tabI + (size_t)(kc + 1) * 32768;
            unsigned char* db = smem + ((kc + 1) & 1) * 32768;
            #pragma unroll
            for (int i = 0; i < 8; ++i)
                gll16(src + (w * 8 + i) * 1024 + lane * 16, db + (w * 8 + i) * 1024);
        }

        // A slices for both M-tiles (8 floats each), split to bf16 hi/lo
        bf16x8 ah[2], al[2];
        #pragma unroll
        for (int m = 0; m < 2; ++m) {
            const float* ar = m ? arow1 : arow0;
            float a[8];
            if (kc < NKC - 1 || lq == 0) {
                const float2* s2 = (const float2*)(ar + kc * 32 + lq * 8);
                float2 p0 = s2[0], p1 = s2[1], p2 = s2[2], p3 = s2[3];
                a[0] = p0.x; a[1] = p0.y; a[2] = p1.x; a[3] = p1.y;
                a[4] = p2.x; a[5] = p2.y; a[6] = p3.x; a[7] = p3.y;
            } else {
                #pragma unroll
                for (int i = 0; i < 8; ++i) a[i] = 0.f;
            }
            split8(a, ah[m], al[m]);
        }

        const unsigned char* Bb = smem + (kc & 1) * 32768;
        #pragma unroll
        for (int nt = 0; nt < 16; ++nt) {
            int off = (nt * 16 + lanelo) * 64 + ((lq ^ sbswz) << 4);
            bf16x8 bh = *(const bf16x8*)(Bb + off);
            bf16x8 bl = *(const bf16x8*)(Bb + 16384 + off);
            #pragma unroll
            for (int m = 0; m < 2; ++m) {
                f32x4 t = acc[m * 16 + nt];
                t = __builtin_amdgcn_mfma_f32_16x16x32_bf16(al[m], bh, t, 0, 0, 0);
                t = __builtin_amdgcn_mfma_f32_16x16x32_bf16(ah[m], bl, t, 0, 0, 0);
                t = __builtin_amdgcn_mfma_f32_16x16x32_bf16(ah[m], bh, t, 0, 0, 0);
                acc[m * 16 + nt] = t;
            }
        }
        __syncthreads();   // B reads done; next buffer committed
    }

    // ---- epilogue per M-tile: mean-correction, log2 magnitude, 128-bin norm,
    //      swizzled-LDS transpose, 64B/lane stores ----
    float* Tw = (float*)(smem + w * 8192);   // safe: all waves past final barrier
    #pragma unroll
    for (int m = 0; m < 2; ++m) {
        // acc[m*16+nt][j]: frame = t0 + w*32 + m*16 + lq*4 + j, col = nt*16+lanelo
        // nt 0..7 = re of bin, nt+8 = im of the SAME bin, same lane.
        float v[8][4];
        #pragma unroll
        for (int nt = 0; nt < 8; ++nt) {
            float orr = ws[WS_OR + nt * 16 + lanelo];
            float oii = ws[WS_OI + nt * 16 + lanelo];
            #pragma unroll
            for (int j = 0; j < 4; ++j) {
                float re = acc[m * 16 + nt][j]     - mu * orr;
                float im = acc[m * 16 + nt + 8][j] - mu * oii;
                float s2 = fmaf(re, re, im * im);
                float lg = 0.5f * __log2f(s2);                // log2(mag)
                v[nt][j] = fmaxf(lg, -23.2534966f);           // log2(1e-7) clamp
            }
        }
        // normalization over 128 bins: 8 in-lane x 16 lanes (same lq = same frame)
        #pragma unroll
        for (int j = 0; j < 4; ++j) {
            float s = 0.f, q = 0.f;
            #pragma unroll
            for (int nt = 0; nt < 8; ++nt) {
                s += v[nt][j];
                q = fmaf(v[nt][j], v[nt][j], q);
            }
            #pragma unroll
            for (int off = 1; off < 16; off <<= 1) {
                s += __shfl_xor(s, off);
                q += __shfl_xor(q, off);
            }
            float mean = s * (1.f / 128.f);
            float var  = fmaxf(q * (1.f / 128.f) - mean * mean, 0.f);
            float sc   = 1.f / (sqrtf(var) + 3.3219281e-7f);  // eps / log10(2)
            #pragma unroll
            for (int nt = 0; nt < 8; ++nt) v[nt][j] = (v[nt][j] - mean) * sc;
        }
        // transpose through per-wave swizzled LDS (same-wave ordering, no barrier)
        #pragma unroll
        for (int nt = 0; nt < 8; ++nt) {
            int n = nt * 16 + lanelo;
            int swzl = (lq ^ (n & 3) ^ ((n >> 2) & 1)) << 2;
            *(float4*)(Tw + n * 16 + swzl) =
                make_float4(v[nt][0], v[nt][1], v[nt][2], v[nt][3]);
        }
        float* ob = out + (size_t)b * NBINS * TFR + t0 + w * 32 + m * 16;
        #pragma unroll
        for (int p = 0; p < 2; ++p) {
            int n = p * 64 + lane;
            int sw = (n & 3) ^ ((n >> 2) & 1);
            float4 r0 = *(float4*)(Tw + n * 16 + ((0 ^ sw) << 2));
            float4 r1 = *(float4*)(Tw + n * 16 + ((1 ^ sw) << 2));
            float4 r2 = *(float4*)(Tw + n * 16 + ((2 ^ sw) << 2));
            float4 r3 = *(float4*)(Tw + n * 16 + ((3 ^ sw) << 2));
            float4* dst = (float4*)(ob + (size_t)n * TFR);
            dst[0] = r0; dst[1] = r1; dst[2] = r2; dst[3] = r3;
        }
    }
}

extern "C" void kernel_launch(void* const* d_in, const int* in_sizes, int n_in,
                              void* d_out, int out_size, void* d_ws, size_t ws_size,
                              hipStream_t stream) {
    const float* x  = (const float*)d_in[0];
    const float* rk = (const float*)d_in[1];
    const float* ik = (const float*)d_in[2];
    float* out = (float*)d_out;
    float* ws  = (float*)d_ws;

    k_aux<<<2288, 256, 0, stream>>>(x, rk, ik, ws);
    k_main<<<dim3(TFR / 128, BATCH), 256, 0, stream>>>(x, ws, out);
}